// Round 1
// baseline (177.479 us; speedup 1.0000x reference)
//
#include <hip/hip_runtime.h>
#include <cmath>

// MHSA cosine-attention block, MI355X/gfx950.
// K1: QKV 1x1-conv projections + L2-normalize(Q,K) -> bf16 (Q,K as [nh][l][k], V as [nh][v][l])
// K2: flash attention, bf16 MFMA 16x16x32, key-split KS=8, fp32 num/den partials to ws
// K3: reduce partials, R/den, output projection (MFMA) + bias + residual

typedef __bf16 bf16x8 __attribute__((ext_vector_type(8)));
typedef float f4_t __attribute__((ext_vector_type(4)));

#define LQ 4096       // sequence length H*W
#define NH 4          // n*heads
#define KS 8          // key splits

__device__ inline f4_t mfma16(bf16x8 a, bf16x8 b, f4_t c) {
    return __builtin_amdgcn_mfma_f32_16x16x32_bf16(a, b, c, 0, 0, 0);
}

// ---------------------------------------------------------------------------
// Kernel 1: QKV projection + normalize.
// grid: 256 blocks = N(2) x 128 l-tiles of 32.  block: 320 thr (5 waves).
// wave g: 0 = Q h0, 1 = Q h1, 2 = K h0, 3 = K h1, 4 = V (lane = h*32+v)
// x reads are wave-uniform (scalar path); W row lives in 64 VGPRs.
// ---------------------------------------------------------------------------
__global__ void k1_qkv(const float* __restrict__ x,
                       const float* __restrict__ Wq, const float* __restrict__ bq,
                       const float* __restrict__ Wk, const float* __restrict__ bk,
                       const float* __restrict__ Wv, const float* __restrict__ bv,
                       __bf16* __restrict__ Qb, __bf16* __restrict__ Kb,
                       __bf16* __restrict__ Vtb) {
    const int tid  = threadIdx.x;
    const int g    = tid >> 6;
    const int lane = tid & 63;
    const int n    = blockIdx.x >> 7;
    const int lt   = blockIdx.x & 127;
    const int l0   = lt * 32;

    __shared__ __bf16 Vl[64][40];   // pitch 40 bf16 = 80B (16B-aligned rows, 2-way banks)

    const float* Wrow;
    float bias;
    if (g == 0)      { Wrow = Wq + lane * 64;        bias = bq[lane]; }
    else if (g == 1) { Wrow = Wq + (64 + lane) * 64; bias = bq[64 + lane]; }
    else if (g == 2) { Wrow = Wk + lane * 64;        bias = bk[lane]; }
    else if (g == 3) { Wrow = Wk + (64 + lane) * 64; bias = bk[64 + lane]; }
    else             { Wrow = Wv + lane * 64;        bias = bv[lane]; }

    float w[64];
#pragma unroll
    for (int c4 = 0; c4 < 16; ++c4) {
        f4_t t = *(const f4_t*)(Wrow + c4 * 4);
        w[c4 * 4 + 0] = t[0]; w[c4 * 4 + 1] = t[1];
        w[c4 * 4 + 2] = t[2]; w[c4 * 4 + 3] = t[3];
    }

    const float* xn = x + (size_t)n * 64 * LQ + l0;

    for (int li = 0; li < 32; ++li) {
        float acc = bias;
#pragma unroll
        for (int c = 0; c < 64; ++c)
            acc = fmaf(w[c], xn[(size_t)c * LQ + li], acc);   // wave-uniform x

        if (g < 4) {
            // L2 normalize across the 64 lanes (= dk)
            float ss = acc * acc;
#pragma unroll
            for (int m = 1; m < 64; m <<= 1) ss += __shfl_xor(ss, m, 64);
            float val = acc * (1.0f / fmaxf(sqrtf(ss), 1e-6f));
            const int h = g & 1;
            __bf16* dst = (g < 2) ? Qb : Kb;
            dst[((size_t)((n * 2 + h) * LQ + l0 + li)) * 64 + lane] = (__bf16)val;
        } else {
            Vl[lane][li] = (__bf16)acc;
        }
    }
    __syncthreads();
    // transpose-write V: Vtb[nh][v][l]
    if (tid < 256) {
        const int row = tid >> 2;          // h*32+v
        const int lb  = (tid & 3) * 8;
        const int h = row >> 5, v = row & 31;
        bf16x8 t = *(const bf16x8*)&Vl[row][lb];
        *(bf16x8*)(Vtb + ((size_t)((n * 2 + h) * 32 + v)) * LQ + l0 + lb) = t;
    }
}

// ---------------------------------------------------------------------------
// Kernel 2: flash attention (no max-tracking: scores in [-1,1]).
// grid: (32 q-blocks of 128, nh=4, ks=8).  block: 256 thr = 4 waves.
// wave owns 32 queries; loops 16 chunks of 32 keys.
// ---------------------------------------------------------------------------
__global__ __launch_bounds__(256, 4) void k2_attn(
        const __bf16* __restrict__ Qb, const __bf16* __restrict__ Kb,
        const __bf16* __restrict__ Vtb,
        float* __restrict__ numP, float* __restrict__ denP) {
    const int lane = threadIdx.x & 63;
    const int wave = threadIdx.x >> 6;
    const int quad = lane >> 4;
    const int l15  = lane & 15;
    const int nh   = blockIdx.y;
    const int ks   = blockIdx.z;
    const int qbase = blockIdx.x * 128 + wave * 32;
    const int kbase = ks * 512;

    __shared__ __bf16 P[4][2][16][40];   // [wave][qtile][q-row][32 keys + pad]

    const f4_t fzero = {0.f, 0.f, 0.f, 0.f};

    // Q fragments: 2 q-tiles x 2 k-dim halves, reused across the whole key loop
    bf16x8 qf[2][2];
#pragma unroll
    for (int qt = 0; qt < 2; ++qt)
#pragma unroll
        for (int kh = 0; kh < 2; ++kh)
            qf[qt][kh] = *(const bf16x8*)(Qb +
                ((size_t)(nh * LQ + qbase + qt * 16 + l15)) * 64 + kh * 32 + quad * 8);

    f4_t racc[2][2];                     // [v-tile][q-tile], R^T accumulators
#pragma unroll
    for (int a = 0; a < 2; ++a)
#pragma unroll
        for (int b = 0; b < 2; ++b) racc[a][b] = fzero;
    float den[2][4] = {};                // [q-tile][C-reg]

    for (int ch = 0; ch < 16; ++ch) {
        const int kb = kbase + ch * 32;

        bf16x8 kf[2][2], vf[2];
#pragma unroll
        for (int kt = 0; kt < 2; ++kt)
#pragma unroll
            for (int kh = 0; kh < 2; ++kh)
                kf[kt][kh] = *(const bf16x8*)(Kb +
                    ((size_t)(nh * LQ + kb + kt * 16 + l15)) * 64 + kh * 32 + quad * 8);
#pragma unroll
        for (int vt = 0; vt < 2; ++vt)
            vf[vt] = *(const bf16x8*)(Vtb +
                ((size_t)(nh * 32 + vt * 16 + l15)) * LQ + kb + quad * 8);

        // S = Q K^T tiles -> exp -> den + P(bf16) in LDS
#pragma unroll
        for (int qt = 0; qt < 2; ++qt) {
#pragma unroll
            for (int kt = 0; kt < 2; ++kt) {
                f4_t s = mfma16(qf[qt][0], kf[kt][0], fzero);
                s      = mfma16(qf[qt][1], kf[kt][1], s);
#pragma unroll
                for (int r = 0; r < 4; ++r) {
                    float p = __expf(s[r]);
                    den[qt][r] += p;
                    P[wave][qt][quad * 4 + r][kt * 16 + l15] = (__bf16)p;
                }
            }
        }
        // PV: A = V^T rows, B = P rows (same-wave LDS round trip; in-order DS)
#pragma unroll
        for (int qt = 0; qt < 2; ++qt) {
            bf16x8 pf = *(const bf16x8*)&P[wave][qt][l15][quad * 8];
#pragma unroll
            for (int vt = 0; vt < 2; ++vt)
                racc[vt][qt] = mfma16(vf[vt], pf, racc[vt][qt]);
        }
    }

    // reduce den across the 16 lanes of each quad (16 key-columns)
#pragma unroll
    for (int qt = 0; qt < 2; ++qt)
#pragma unroll
        for (int r = 0; r < 4; ++r) {
#pragma unroll
            for (int m = 1; m < 16; m <<= 1)
                den[qt][r] += __shfl_xor(den[qt][r], m, 16);
        }

    // write num partials: [nh][ks][v(32)][q(4096)]
#pragma unroll
    for (int vt = 0; vt < 2; ++vt)
#pragma unroll
        for (int qt = 0; qt < 2; ++qt)
#pragma unroll
            for (int r = 0; r < 4; ++r)
                numP[((size_t)((nh * KS + ks) * 32 + vt * 16 + quad * 4 + r)) * LQ
                     + qbase + qt * 16 + l15] = racc[vt][qt][r];

    // write den partials: [nh][ks][q]
#pragma unroll
    for (int qt = 0; qt < 2; ++qt)
#pragma unroll
        for (int r = 0; r < 4; ++r)
            if (l15 == r)
                denP[(size_t)(nh * KS + ks) * LQ + qbase + qt * 16 + quad * 4 + r]
                    = den[qt][r];
}

// ---------------------------------------------------------------------------
// Kernel 3: reduce partials -> R, output projection (MFMA) + bias + residual.
// grid: 128 blocks = N(2) x 64 l-tiles of 64.  block: 256 thr = 4 waves.
// ---------------------------------------------------------------------------
__global__ __launch_bounds__(256) void k3_out(
        const float* __restrict__ numP, const float* __restrict__ denP,
        const float* __restrict__ Wm, const float* __restrict__ bm,
        const float* __restrict__ x, float* __restrict__ out) {
    const int tid  = threadIdx.x;
    const int lane = tid & 63;
    const int wave = tid >> 6;
    const int quad = lane >> 4;
    const int l15  = lane & 15;
    const int n    = blockIdx.x >> 6;
    const int lt   = blockIdx.x & 63;
    const int l0   = lt * 64;

    __shared__ __bf16 Rl[64][72];     // [l][j=h*32+v], pitch 144B
    __shared__ __bf16 Wl[64][72];     // [o][j]
    __shared__ float  dinv[2][64];

    const f4_t fzero = {0.f, 0.f, 0.f, 0.f};

    // stage Wm (64x64 fp32) as bf16
    for (int i = tid; i < 4096; i += 256) Wl[i >> 6][i & 63] = (__bf16)Wm[i];
    // denominator sums -> reciprocal
    if (tid < 128) {
        const int hh = tid >> 6, li = tid & 63;
        float s = 0.f;
#pragma unroll
        for (int k = 0; k < KS; ++k)
            s += denP[((size_t)((n * 2 + hh) * KS + k)) * LQ + l0 + li];
        dinv[hh][li] = 1.0f / s;
    }
    __syncthreads();

    // build R tile: wave w covers l in [w*16, w*16+16), lane = j
    {
        const int j = lane, v = j & 31, hh = j >> 5;
        f4_t a[4] = {fzero, fzero, fzero, fzero};
#pragma unroll
        for (int k = 0; k < KS; ++k) {
            const float* p = numP +
                ((size_t)(((n * 2 + hh) * KS + k) * 32 + v)) * LQ + l0 + wave * 16;
#pragma unroll
            for (int i = 0; i < 4; ++i) a[i] += *(const f4_t*)(p + i * 4);
        }
#pragma unroll
        for (int i = 0; i < 4; ++i)
#pragma unroll
            for (int e = 0; e < 4; ++e) {
                const int li = wave * 16 + i * 4 + e;
                Rl[li][j] = (__bf16)(a[i][e] * dinv[hh][li]);
            }
    }
    __syncthreads();

    // out tile [64 o x 16 l] per wave via MFMA: A = Wm rows, B = R
    f4_t acc[4] = {fzero, fzero, fzero, fzero};
#pragma unroll
    for (int kc = 0; kc < 2; ++kc) {
        bf16x8 bfr = *(const bf16x8*)&Rl[wave * 16 + l15][kc * 32 + quad * 8];
#pragma unroll
        for (int ot = 0; ot < 4; ++ot) {
            bf16x8 afr = *(const bf16x8*)&Wl[ot * 16 + l15][kc * 32 + quad * 8];
            acc[ot] = mfma16(afr, bfr, acc[ot]);
        }
    }

    // epilogue: + bm + residual, coalesced fp32
#pragma unroll
    for (int ot = 0; ot < 4; ++ot)
#pragma unroll
        for (int r = 0; r < 4; ++r) {
            const int o = ot * 16 + quad * 4 + r;
            const int l = l0 + wave * 16 + l15;
            const size_t idx = ((size_t)(n * 64 + o)) * LQ + l;
            out[idx] = acc[ot][r] + bm[o] + x[idx];
        }
}

// ---------------------------------------------------------------------------
extern "C" void kernel_launch(void* const* d_in, const int* in_sizes, int n_in,
                              void* d_out, int out_size, void* d_ws, size_t ws_size,
                              hipStream_t stream) {
    const float* x  = (const float*)d_in[0];
    const float* Wq = (const float*)d_in[1];
    const float* bq = (const float*)d_in[2];
    const float* Wk = (const float*)d_in[3];
    const float* bk = (const float*)d_in[4];
    const float* Wv = (const float*)d_in[5];
    const float* bv = (const float*)d_in[6];
    const float* Wm = (const float*)d_in[7];
    const float* bm = (const float*)d_in[8];
    float* out = (float*)d_out;

    // workspace carve (bytes): Qb 2MB | Kb 2MB | Vtb 1MB | numP 16MB | denP 0.5MB
    __bf16* Qb  = (__bf16*)d_ws;
    __bf16* Kb  = Qb + (size_t)NH * LQ * 64;
    __bf16* Vtb = Kb + (size_t)NH * LQ * 64;
    float*  numP = (float*)(Vtb + (size_t)NH * 32 * LQ);
    float*  denP = numP + (size_t)NH * KS * 32 * LQ;

    k1_qkv<<<dim3(256), dim3(320), 0, stream>>>(x, Wq, bq, Wk, bk, Wv, bv,
                                                Qb, Kb, Vtb);
    k2_attn<<<dim3(32, NH, KS), dim3(256), 0, stream>>>(Qb, Kb, Vtb, numP, denP);
    k3_out<<<dim3(128), dim3(256), 0, stream>>>(numP, denP, Wm, bm, x, out);
}